// Round 1
// baseline (669.738 us; speedup 1.0000x reference)
//
#include <hip/hip_runtime.h>
#include <hip/hip_bf16.h>

#define NN 50000
#define IN_DIM 256
#define HID 128
#define CCH 2
#define RR 5
#define LL 2
#define NCLS 16

// ---------------- Filt: softmax over R for each (l,c) ----------------
__global__ void filt_kernel(const float* __restrict__ gt_w, float* __restrict__ filt) {
    int t = threadIdx.x;  // L*C = 4 softmaxes
    if (t < LL * CCH) {
        const float* g = gt_w + t * RR;
        float m = -1e30f;
        for (int r = 0; r < RR; ++r) m = fmaxf(m, g[r]);
        float e[RR], s = 0.f;
        for (int r = 0; r < RR; ++r) { e[r] = __expf(g[r] - m); s += e[r]; }
        for (int r = 0; r < RR; ++r) filt[t * RR + r] = e[r] / s;
    }
}

// ---------------- Projection: H0[c][n][d] = sum_k h[n][k] * Wc[c][k][d] ----------------
#define NPB 16
__global__ void proj_kernel(const float* __restrict__ h, const float* __restrict__ Wc,
                            float* __restrict__ H0, int N) {
    int t = threadIdx.x;           // 256 threads: c = t>>7, d = t&127
    int c = t >> 7, d = t & 127;
    int n0 = blockIdx.x * NPB;
    __shared__ float hs[NPB][IN_DIM];
    for (int idx = t; idx < NPB * IN_DIM; idx += 256) {
        int m = idx >> 8, k = idx & 255;
        int n = n0 + m;
        hs[m][k] = (n < N) ? h[(size_t)n * IN_DIM + k] : 0.f;
    }
    __syncthreads();
    float acc[NPB];
#pragma unroll
    for (int m = 0; m < NPB; ++m) acc[m] = 0.f;
    const float* W = Wc + (size_t)c * IN_DIM * HID + d;
    for (int k = 0; k < IN_DIM; ++k) {
        float w = W[(size_t)k * HID];
#pragma unroll
        for (int m = 0; m < NPB; ++m) acc[m] += hs[m][k] * w;
    }
#pragma unroll
    for (int m = 0; m < NPB; ++m) {
        int n = n0 + m;
        if (n < N) H0[(size_t)c * N * HID + (size_t)n * HID + d] = acc[m];
    }
}

// ---------------- CSR build ----------------
__global__ void count_kernel(const int* __restrict__ dst, int* __restrict__ counts, int E) {
    for (int e = blockIdx.x * blockDim.x + threadIdx.x; e < E; e += gridDim.x * blockDim.x)
        atomicAdd(&counts[dst[e]], 1);
}

__global__ void scan_kernel(const int* __restrict__ counts, int* __restrict__ offsets, int n) {
    // single block, 1024 threads; chunked Hillis-Steele inclusive scan
    __shared__ int lds[1024];
    __shared__ int running;
    int tid = threadIdx.x;
    if (tid == 0) { running = 0; offsets[0] = 0; }
    __syncthreads();
    for (int base = 0; base < n; base += 1024) {
        int i = base + tid;
        int v = (i < n) ? counts[i] : 0;
        lds[tid] = v;
        __syncthreads();
        for (int off = 1; off < 1024; off <<= 1) {
            int tv = (tid >= off) ? lds[tid - off] : 0;
            __syncthreads();
            lds[tid] += tv;
            __syncthreads();
        }
        if (i < n) offsets[i + 1] = running + lds[tid];
        __syncthreads();
        if (tid == 1023) running += lds[1023];
        __syncthreads();
    }
}

__global__ void cursor_kernel(const int* __restrict__ offsets, int* __restrict__ cursor, int n) {
    int i = blockIdx.x * blockDim.x + threadIdx.x;
    if (i < n) cursor[i] = offsets[i];
}

__global__ void fill_kernel(const int* __restrict__ src, const int* __restrict__ dst,
                            const int* __restrict__ etype, int* __restrict__ cursor,
                            int* __restrict__ ssrc, int* __restrict__ set_, int E) {
    for (int e = blockIdx.x * blockDim.x + threadIdx.x; e < E; e += gridDim.x * blockDim.x) {
        int d = dst[e];
        int p = atomicAdd(&cursor[d], 1);
        ssrc[p] = src[e];
        set_[p] = etype[e];
    }
}

// ---------------- Aggregation: one block per dst node ----------------
// Hout[c][n][d] = (sum_e w_e * Hin[c][src_e][d]) / (sum_e w_e),  w_e = Filt[c][et_e]
__global__ void agg_kernel(const float* __restrict__ Hin, float* __restrict__ Hout,
                           const int* __restrict__ offs, const int* __restrict__ ssrc,
                           const int* __restrict__ set_, const float* __restrict__ filt,
                           int N) {
    int n = blockIdx.x;
    int t = threadIdx.x;          // 256: c = t>>7, d = t&127
    int c = t >> 7, d = t & 127;
    __shared__ float f[CCH * RR];
    if (t < CCH * RR) f[t] = filt[t];
    __syncthreads();
    int e0 = offs[n], e1 = offs[n + 1];
    const float* Hc = Hin + (size_t)c * N * HID;
    float acc = 0.f, deg = 0.f;
    for (int j = e0; j < e1; ++j) {
        int s = ssrc[j];
        float w = f[c * RR + set_[j]];
        deg += w;
        acc += w * Hc[(size_t)s * HID + d];
    }
    Hout[(size_t)c * N * HID + (size_t)n * HID + d] = acc / deg;
}

// ---------------- MLP on selected rows ----------------
__global__ void mlp_kernel(const float* __restrict__ Hfin, const int* __restrict__ cat,
                           const float* __restrict__ W1, const float* __restrict__ b1,
                           const float* __restrict__ W2, const float* __restrict__ b2,
                           float* __restrict__ out, int N) {
    int i = blockIdx.x;
    int node = cat[i];
    int t = threadIdx.x;  // 128
    __shared__ float x[CCH * HID];
    __shared__ float hid[HID];
    x[t]       = Hfin[(size_t)node * HID + t];                       // c=0
    x[HID + t] = Hfin[(size_t)N * HID + (size_t)node * HID + t];     // c=1
    __syncthreads();
    float acc = b1[t];
    for (int k = 0; k < CCH * HID; ++k) acc += x[k] * W1[(size_t)k * HID + t];
    hid[t] = fmaxf(acc, 0.f);
    __syncthreads();
    if (t < NCLS) {
        float y = b2[t];
        for (int j = 0; j < HID; ++j) y += hid[j] * W2[(size_t)j * NCLS + t];
        out[(size_t)i * NCLS + t] = y;
    }
}

extern "C" void kernel_launch(void* const* d_in, const int* in_sizes, int n_in,
                              void* d_out, int out_size, void* d_ws, size_t ws_size,
                              hipStream_t stream) {
    const float* h      = (const float*)d_in[0];
    const int* src      = (const int*)d_in[1];
    const int* dst      = (const int*)d_in[2];
    const int* etype    = (const int*)d_in[3];
    const int* cat      = (const int*)d_in[4];
    const float* gt_w   = (const float*)d_in[5];
    const float* Wc     = (const float*)d_in[6];
    const float* W1     = (const float*)d_in[7];
    const float* b1     = (const float*)d_in[8];
    const float* W2     = (const float*)d_in[9];
    const float* b2     = (const float*)d_in[10];
    float* out = (float*)d_out;

    const int N = in_sizes[0] / IN_DIM;     // 50000
    const int E = in_sizes[1];              // 500000
    const int NCAT = in_sizes[4];           // 10000

    // workspace layout
    char* p = (char*)d_ws;
    auto alloc = [&](size_t bytes) {
        char* q = p;
        p += (bytes + 255) & ~(size_t)255;
        return q;
    };
    float* HA      = (float*)alloc((size_t)CCH * N * HID * sizeof(float));
    float* HB      = (float*)alloc((size_t)CCH * N * HID * sizeof(float));
    int*   counts  = (int*)alloc((size_t)N * sizeof(int));
    int*   offsets = (int*)alloc((size_t)(N + 1) * sizeof(int));
    int*   cursor  = (int*)alloc((size_t)N * sizeof(int));
    int*   ssrc    = (int*)alloc((size_t)E * sizeof(int));
    int*   set_    = (int*)alloc((size_t)E * sizeof(int));
    float* filt    = (float*)alloc((size_t)LL * CCH * RR * sizeof(float));

    hipMemsetAsync(counts, 0, (size_t)N * sizeof(int), stream);

    filt_kernel<<<1, 64, 0, stream>>>(gt_w, filt);
    proj_kernel<<<(N + NPB - 1) / NPB, 256, 0, stream>>>(h, Wc, HA, N);

    count_kernel<<<1024, 256, 0, stream>>>(dst, counts, E);
    scan_kernel<<<1, 1024, 0, stream>>>(counts, offsets, N);
    cursor_kernel<<<(N + 255) / 256, 256, 0, stream>>>(offsets, cursor, N);
    fill_kernel<<<1024, 256, 0, stream>>>(src, dst, etype, cursor, ssrc, set_, E);

    agg_kernel<<<N, 256, 0, stream>>>(HA, HB, offsets, ssrc, set_, filt, N);          // layer 0
    agg_kernel<<<N, 256, 0, stream>>>(HB, HA, offsets, ssrc, set_, filt + CCH * RR, N); // layer 1

    mlp_kernel<<<NCAT, 128, 0, stream>>>(HA, cat, W1, b1, W2, b2, out, N);
}

// Round 2
// 446.233 us; speedup vs baseline: 1.5009x; 1.5009x over previous
//
#include <hip/hip_runtime.h>
#include <hip/hip_bf16.h>

#define IN_DIM 256
#define HID 128
#define CCH 2
#define RR 5
#define LL 2
#define NCLS 16

typedef __attribute__((ext_vector_type(8))) short short8;
typedef __attribute__((ext_vector_type(4))) short short4_;
typedef __attribute__((ext_vector_type(4))) float floatx4;

__device__ __forceinline__ unsigned short f2bf(float f) {
    unsigned int u = __float_as_uint(f);
    unsigned int r = (u + 0x7FFFu + ((u >> 16) & 1u)) >> 16;   // RN-even
    return (unsigned short)r;
}
__device__ __forceinline__ float bf2f(unsigned short b) {
    return __uint_as_float(((unsigned int)b) << 16);
}

// ---------------- Filt: softmax over R for each (l,c) ----------------
__global__ void filt_kernel(const float* __restrict__ gt_w, float* __restrict__ filt) {
    int t = threadIdx.x;
    if (t < LL * CCH) {
        const float* g = gt_w + t * RR;
        float m = -1e30f;
        for (int r = 0; r < RR; ++r) m = fmaxf(m, g[r]);
        float e[RR], s = 0.f;
        for (int r = 0; r < RR; ++r) { e[r] = __expf(g[r] - m); s += e[r]; }
        for (int r = 0; r < RR; ++r) filt[t * RR + r] = e[r] / s;
    }
}

// ---------------- weight convert/transpose: WcT[c][d][k], W1T[d][k] (bf16) ----------------
__global__ void cvt_weights(const float* __restrict__ Wc, const float* __restrict__ W1,
                            unsigned short* __restrict__ WcT, unsigned short* __restrict__ W1T) {
    int i = blockIdx.x * 256 + threadIdx.x;
    if (i < CCH * HID * IN_DIM) {            // 65536
        int c = i >> 15;
        int rem = i & 32767;
        int d = rem >> 8;
        int k = rem & 255;
        WcT[i] = f2bf(Wc[((size_t)c * IN_DIM + k) * HID + d]);
    }
    if (i < HID * IN_DIM) {                  // 32768
        int d = i >> 8;
        int k = i & 255;
        W1T[i] = f2bf(W1[(size_t)k * HID + d]);
    }
}

// ---------------- Projection via MFMA: H0[c][n][d] (bf16) ----------------
// A = WcT (M=256 rows over c,d ; K=256), B = h rows (N=nodes), D[m][node]
__global__ __launch_bounds__(256) void proj_mfma(const float* __restrict__ h,
                                                 const unsigned short* __restrict__ WcT,
                                                 unsigned short* __restrict__ H0, int N) {
    int t = threadIdx.x;
    int wv = t >> 6, l = t & 63;
    int l15 = l & 15, lq = l >> 4;
    int node = blockIdx.x * 64 + wv * 16 + l15;
    int nclamp = node < N ? node : N - 1;

    // B fragments: h row -> bf16, 8 k-steps
    short8 bfrag[8];
    const float* hrow = h + (size_t)nclamp * IN_DIM;
#pragma unroll
    for (int kk = 0; kk < 8; ++kk) {
        int k0 = kk * 32 + lq * 8;
        floatx4 f0 = *(const floatx4*)(hrow + k0);
        floatx4 f1 = *(const floatx4*)(hrow + k0 + 4);
        short8 b;
        b[0] = (short)f2bf(f0[0]); b[1] = (short)f2bf(f0[1]);
        b[2] = (short)f2bf(f0[2]); b[3] = (short)f2bf(f0[3]);
        b[4] = (short)f2bf(f1[0]); b[5] = (short)f2bf(f1[1]);
        b[6] = (short)f2bf(f1[2]); b[7] = (short)f2bf(f1[3]);
        bfrag[kk] = b;
    }

#pragma unroll
    for (int mt = 0; mt < 16; ++mt) {
        floatx4 acc = {0.f, 0.f, 0.f, 0.f};
        const unsigned short* arow = WcT + (size_t)(mt * 16 + l15) * IN_DIM;
#pragma unroll
        for (int kk = 0; kk < 8; ++kk) {
            short8 a = *(const short8*)(arow + kk * 32 + lq * 8);
            acc = __builtin_amdgcn_mfma_f32_16x16x32_bf16(a, bfrag[kk], acc, 0, 0, 0);
        }
        if (node < N) {
            int m0 = mt * 16 + lq * 4;          // 0..255 over (c,d)
            int c = m0 >> 7, dd = m0 & 127;
            short4_ st;
            st[0] = (short)f2bf(acc[0]); st[1] = (short)f2bf(acc[1]);
            st[2] = (short)f2bf(acc[2]); st[3] = (short)f2bf(acc[3]);
            *(short4_*)(H0 + ((size_t)c * N + node) * HID + dd) = st;
        }
    }
}

// ---------------- CSR build ----------------
__global__ void count_kernel(const int* __restrict__ dst, int* __restrict__ counts, int E) {
    for (int e = blockIdx.x * blockDim.x + threadIdx.x; e < E; e += gridDim.x * blockDim.x)
        atomicAdd(&counts[dst[e]], 1);
}

// phase A: per-chunk totals (chunk = 256)
__global__ void scanA_kernel(const int* __restrict__ counts, int* __restrict__ partials, int n) {
    __shared__ int s[256];
    int t = threadIdx.x;
    int i = blockIdx.x * 256 + t;
    int v = (i < n) ? counts[i] : 0;
    s[t] = v;
    __syncthreads();
    for (int off = 1; off < 256; off <<= 1) {
        int tv = (t >= off) ? s[t - off] : 0;
        __syncthreads();
        s[t] += tv;
        __syncthreads();
    }
    if (t == 255) partials[blockIdx.x] = s[255];
}

// phase B: exclusive scan of chunk totals (nchunk <= 256)
__global__ void scanB_kernel(const int* __restrict__ partials, int* __restrict__ chunk_off, int nchunk) {
    __shared__ int s[256];
    int t = threadIdx.x;
    int v = (t < nchunk) ? partials[t] : 0;
    s[t] = v;
    __syncthreads();
    for (int off = 1; off < 256; off <<= 1) {
        int tv = (t >= off) ? s[t - off] : 0;
        __syncthreads();
        s[t] += tv;
        __syncthreads();
    }
    if (t < nchunk) chunk_off[t] = s[t] - v;   // exclusive
}

// phase C: final offsets + cursor
__global__ void scanC_kernel(const int* __restrict__ counts, const int* __restrict__ chunk_off,
                             int* __restrict__ offsets, int* __restrict__ cursor, int n) {
    __shared__ int s[256];
    int t = threadIdx.x;
    int i = blockIdx.x * 256 + t;
    int v = (i < n) ? counts[i] : 0;
    s[t] = v;
    __syncthreads();
    for (int off = 1; off < 256; off <<= 1) {
        int tv = (t >= off) ? s[t - off] : 0;
        __syncthreads();
        s[t] += tv;
        __syncthreads();
    }
    if (i < n) {
        int incl = chunk_off[blockIdx.x] + s[t];
        offsets[i + 1] = incl;
        cursor[i] = incl - v;
    }
    if (i == 0) offsets[0] = 0;
}

__global__ void fill_kernel(const int* __restrict__ src, const int* __restrict__ dst,
                            const int* __restrict__ etype, int* __restrict__ cursor,
                            int* __restrict__ ssrc, int* __restrict__ set_, int E) {
    for (int e = blockIdx.x * blockDim.x + threadIdx.x; e < E; e += gridDim.x * blockDim.x) {
        int d = dst[e];
        int p = atomicAdd(&cursor[d], 1);
        ssrc[p] = src[e];
        set_[p] = etype[e];
    }
}

// ---------------- Aggregation (bf16 in/out): 2 nodes x (2ch x 64 lanes) per block ----------------
__global__ __launch_bounds__(256) void agg_kernel(const unsigned int* __restrict__ Hin,
                                                  unsigned int* __restrict__ Hout,
                                                  const int* __restrict__ offs,
                                                  const int* __restrict__ ssrc,
                                                  const int* __restrict__ set_,
                                                  const float* __restrict__ filt, int N) {
    int t = threadIdx.x;
    int node = blockIdx.x * 2 + (t >> 7);
    if (node >= N) return;
    int c = (t >> 6) & 1;
    int lane = t & 63;
    float fw[RR];
#pragma unroll
    for (int r = 0; r < RR; ++r) fw[r] = filt[c * RR + r];
    int e0 = offs[node], e1 = offs[node + 1];
    const unsigned int* Hc = Hin + (size_t)c * N * 64;   // row = 64 uints (128 bf16)
    float ax = 0.f, ay = 0.f, deg = 0.f;
    for (int j = e0; j < e1; ++j) {
        int s = ssrc[j];
        float w = fw[set_[j]];
        unsigned int v = Hc[(size_t)s * 64 + lane];
        ax += w * __uint_as_float(v << 16);
        ay += w * __uint_as_float(v & 0xFFFF0000u);
        deg += w;
    }
    float inv = 1.f / deg;
    unsigned int lo = f2bf(ax * inv);
    unsigned int hi = f2bf(ay * inv);
    Hout[((size_t)c * N + node) * 64 + lane] = lo | (hi << 16);
}

// ---------------- MLP1 via MFMA on gathered rows: hidden[i][d] = relu(X@W1+b1) ----------------
__global__ __launch_bounds__(256) void mlp1_mfma(const unsigned short* __restrict__ H2,
                                                 const int* __restrict__ cat,
                                                 const unsigned short* __restrict__ W1T,
                                                 const float* __restrict__ b1,
                                                 float* __restrict__ hidden, int N, int NCAT) {
    int t = threadIdx.x;
    int wv = t >> 6, l = t & 63;
    int l15 = l & 15, lq = l >> 4;
    int i = blockIdx.x * 64 + wv * 16 + l15;
    int iclamp = i < NCAT ? i : NCAT - 1;
    int node = cat[iclamp];

    short8 bfrag[8];
#pragma unroll
    for (int kk = 0; kk < 8; ++kk) {
        const unsigned short* base = (kk < 4)
            ? H2 + (size_t)node * HID + kk * 32
            : H2 + (size_t)N * HID + (size_t)node * HID + (kk - 4) * 32;
        bfrag[kk] = *(const short8*)(base + lq * 8);
    }

#pragma unroll
    for (int mt = 0; mt < 8; ++mt) {
        floatx4 acc = {0.f, 0.f, 0.f, 0.f};
        const unsigned short* arow = W1T + (size_t)(mt * 16 + l15) * (CCH * HID);
#pragma unroll
        for (int kk = 0; kk < 8; ++kk) {
            short8 a = *(const short8*)(arow + kk * 32 + lq * 8);
            acc = __builtin_amdgcn_mfma_f32_16x16x32_bf16(a, bfrag[kk], acc, 0, 0, 0);
        }
        if (i < NCAT) {
            int d0 = mt * 16 + lq * 4;
            floatx4 o;
#pragma unroll
            for (int r = 0; r < 4; ++r) o[r] = fmaxf(acc[r] + b1[d0 + r], 0.f);
            *(floatx4*)(hidden + (size_t)i * HID + d0) = o;
        }
    }
}

// ---------------- MLP2: out[i][cls] = hidden[i]@W2 + b2 ----------------
__global__ void mlp2_kernel(const float* __restrict__ hidden, const float* __restrict__ W2,
                            const float* __restrict__ b2, float* __restrict__ out, int NCAT) {
    int idx = blockIdx.x * 256 + threadIdx.x;
    int i = idx >> 4, cls = idx & 15;
    if (i >= NCAT) return;
    const float* hrow = hidden + (size_t)i * HID;
    float acc = b2[cls];
#pragma unroll 8
    for (int j = 0; j < HID; ++j) acc += hrow[j] * W2[j * NCLS + cls];
    out[idx] = acc;
}

extern "C" void kernel_launch(void* const* d_in, const int* in_sizes, int n_in,
                              void* d_out, int out_size, void* d_ws, size_t ws_size,
                              hipStream_t stream) {
    const float* h    = (const float*)d_in[0];
    const int* src    = (const int*)d_in[1];
    const int* dst    = (const int*)d_in[2];
    const int* etype  = (const int*)d_in[3];
    const int* cat    = (const int*)d_in[4];
    const float* gt_w = (const float*)d_in[5];
    const float* Wc   = (const float*)d_in[6];
    const float* W1   = (const float*)d_in[7];
    const float* b1   = (const float*)d_in[8];
    const float* W2   = (const float*)d_in[9];
    const float* b2   = (const float*)d_in[10];
    float* out = (float*)d_out;

    const int N = in_sizes[0] / IN_DIM;   // 50000
    const int E = in_sizes[1];            // 500000
    const int NCAT = in_sizes[4];         // 10000
    const int NCHUNK = (N + 255) / 256;   // 196

    char* p = (char*)d_ws;
    auto alloc = [&](size_t bytes) {
        char* q = p;
        p += (bytes + 255) & ~(size_t)255;
        return q;
    };
    unsigned short* HA   = (unsigned short*)alloc((size_t)CCH * N * HID * 2);
    unsigned short* HB   = (unsigned short*)alloc((size_t)CCH * N * HID * 2);
    unsigned short* WcT  = (unsigned short*)alloc((size_t)CCH * HID * IN_DIM * 2);
    unsigned short* W1T  = (unsigned short*)alloc((size_t)HID * CCH * HID * 2);
    float* hidden        = (float*)alloc((size_t)NCAT * HID * 4);
    int*   counts        = (int*)alloc((size_t)N * 4);
    int*   offsets       = (int*)alloc((size_t)(N + 1) * 4);
    int*   cursor        = (int*)alloc((size_t)N * 4);
    int*   partials      = (int*)alloc((size_t)NCHUNK * 4);
    int*   chunk_off     = (int*)alloc((size_t)NCHUNK * 4);
    int*   ssrc          = (int*)alloc((size_t)E * 4);
    int*   set_          = (int*)alloc((size_t)E * 4);
    float* filt          = (float*)alloc((size_t)LL * CCH * RR * 4);

    hipMemsetAsync(counts, 0, (size_t)N * 4, stream);

    filt_kernel<<<1, 64, 0, stream>>>(gt_w, filt);
    cvt_weights<<<(CCH * HID * IN_DIM + 255) / 256, 256, 0, stream>>>(Wc, W1, WcT, W1T);
    proj_mfma<<<(N + 63) / 64, 256, 0, stream>>>(h, WcT, HA, N);

    count_kernel<<<512, 256, 0, stream>>>(dst, counts, E);
    scanA_kernel<<<NCHUNK, 256, 0, stream>>>(counts, partials, N);
    scanB_kernel<<<1, 256, 0, stream>>>(partials, chunk_off, NCHUNK);
    scanC_kernel<<<NCHUNK, 256, 0, stream>>>(counts, chunk_off, offsets, cursor, N);
    fill_kernel<<<512, 256, 0, stream>>>(src, dst, etype, cursor, ssrc, set_, E);

    agg_kernel<<<(N + 1) / 2, 256, 0, stream>>>((const unsigned int*)HA, (unsigned int*)HB,
                                                offsets, ssrc, set_, filt, N);
    agg_kernel<<<(N + 1) / 2, 256, 0, stream>>>((const unsigned int*)HB, (unsigned int*)HA,
                                                offsets, ssrc, set_, filt + CCH * RR, N);

    mlp1_mfma<<<(NCAT + 63) / 64, 256, 0, stream>>>(HA, cat, W1T, b1, hidden, N, NCAT);
    mlp2_kernel<<<(NCAT * NCLS + 255) / 256, 256, 0, stream>>>(hidden, W2, b2, out, NCAT);
}